// Round 3
// baseline (305.597 us; speedup 1.0000x reference)
//
#include <hip/hip_runtime.h>
#include <stdint.h>

#define B_SZ 8192
#define D_SZ 1024
#define L_SZ 64
#define H_SZ 256

#define BM 256
#define BN 256
#define BK 64

typedef __attribute__((ext_vector_type(8))) __bf16 bf16x8;
typedef __attribute__((ext_vector_type(4))) float f32x4;

typedef __attribute__((address_space(1))) void as1_void;
typedef __attribute__((address_space(3))) void as3_void;

static __device__ __forceinline__ void gload_lds16(const void* g, void* l) {
    __builtin_amdgcn_global_load_lds((as1_void*)g, (as3_void*)l, 16, 0, 0);
}

static __device__ __forceinline__ unsigned short f2bf(float f) {
    uint32_t u = __builtin_bit_cast(uint32_t, f);
    u += 0x7fffu + ((u >> 16) & 1u);
    return (unsigned short)(u >> 16);
}

// ---------------- prep: x (fp32 [B][D]) -> bf16 ----------------
__global__ void cvt_x_kernel(const float* __restrict__ x, unsigned short* __restrict__ xb) {
    int i = blockIdx.x * blockDim.x + threadIdx.x;
    const float4 v = reinterpret_cast<const float4*>(x)[i];
    ushort4 o;
    o.x = f2bf(v.x); o.y = f2bf(v.y); o.z = f2bf(v.z); o.w = f2bf(v.w);
    reinterpret_cast<ushort4*>(xb)[i] = o;
}

// ------- prep: W1 (fp32 [L][D][H]) -> W1T bf16 [L][H][D] -------
__global__ void transpose_w1_kernel(const float* __restrict__ w1, unsigned short* __restrict__ w1t) {
    __shared__ float tile[64][65];
    int b = blockIdx.x;
    int l  = b >> 6;
    int dt = (b >> 2) & 15;
    int ht = b & 3;
    int tx = threadIdx.x & 63;
    int ty = threadIdx.x >> 6;
    const float* src = w1 + (size_t)l * (D_SZ * H_SZ);
    #pragma unroll
    for (int r = 0; r < 64; r += 4)
        tile[r + ty][tx] = src[(size_t)(dt * 64 + r + ty) * H_SZ + ht * 64 + tx];
    __syncthreads();
    unsigned short* dst = w1t + (size_t)l * (H_SZ * D_SZ);
    #pragma unroll
    for (int r = 0; r < 64; r += 4)
        dst[(size_t)(ht * 64 + r + ty) * D_SZ + dt * 64 + tx] = f2bf(tile[tx][r + ty]);
}

// -------- persistent fused label-wise FFN GEMM, 256x256 8-phase --------
// grid: 256 blocks (1/CU), 512 threads (8 waves, 2M x 4N).
// Block b: label l = (b&7)*8 + ((b>>3)&7)  (8 labels resident per XCD),
// gi = b>>6; computes 8 output tiles m-tile = gi*8+o, o=0..7, as ONE
// continuous K-tile stream (no per-tile prologue/tail drain).

#define SBAR asm volatile("s_barrier" ::: "memory")
#define VMW(n) asm volatile("s_waitcnt vmcnt(" #n ")" ::: "memory")

#define DS_READ_A(c, quad) do { \
    _Pragma("unroll") for (int j = 0; j < 2; ++j) { \
        const int rowh = ((quad)*2 + j)*16 + rl; \
        _Pragma("unroll") for (int ks = 0; ks < 2; ++ks) { \
            const int slot = (ks*4 + g) ^ (rowh & 7); \
            af[ks][j] = *reinterpret_cast<const bf16x8*>( \
                reinterpret_cast<const char*>(&ldsAB[c][0][wr][0]) + rowh*128 + slot*16); \
        } } } while(0)

#define DS_READ_B(c) do { \
    _Pragma("unroll") for (int nf = 0; nf < 4; ++nf) { \
        const int rowb = wc*64 + nf*16 + rl; \
        const int bh = rowb >> 7; \
        const int rowh = rowb & 127; \
        _Pragma("unroll") for (int ks = 0; ks < 2; ++ks) { \
            const int slot = (ks*4 + g) ^ (rowh & 7); \
            bf[ks][nf] = *reinterpret_cast<const bf16x8*>( \
                reinterpret_cast<const char*>(&ldsAB[c][1][bh][0]) + rowh*128 + slot*16); \
        } } } while(0)

#define MFMA_QUAD(quad) do { \
    __builtin_amdgcn_s_setprio(1); \
    _Pragma("unroll") for (int ks = 0; ks < 2; ++ks) \
    _Pragma("unroll") for (int j = 0; j < 2; ++j) \
    _Pragma("unroll") for (int nf = 0; nf < 4; ++nf) \
        acc[(quad)*2 + j][nf] = __builtin_amdgcn_mfma_f32_16x16x32_bf16( \
            af[ks][j], bf[ks][nf], acc[(quad)*2 + j][nf], 0, 0, 0); \
    __builtin_amdgcn_s_setprio(0); } while(0)

#define STAGE_A(t, h) do { \
    gload_lds16(aSrc[h][0] + (size_t)(t)*BK, &ldsAB[(t)&1][0][h][(wid*64)*8]); \
    gload_lds16(aSrc[h][1] + (size_t)(t)*BK, &ldsAB[(t)&1][0][h][(512 + wid*64)*8]); } while(0)

// next output tile's A(0): aSrc + 256 rows (lands in buf0; t'=0 parity)
#define STAGE_AN(h) do { \
    gload_lds16(aSrc[h][0] + ADV, &ldsAB[0][0][h][(wid*64)*8]); \
    gload_lds16(aSrc[h][1] + ADV, &ldsAB[0][0][h][(512 + wid*64)*8]); } while(0)

#define STAGE_B(t, h) do { \
    gload_lds16(bSrc[h][0] + (size_t)(t)*BK, &ldsAB[(t)&1][1][h][(wid*64)*8]); \
    gload_lds16(bSrc[h][1] + (size_t)(t)*BK, &ldsAB[(t)&1][1][h][(512 + wid*64)*8]); } while(0)

__global__ __launch_bounds__(512, 2) void ffn_gemm_kernel(
    const unsigned short* __restrict__ xb,    // bf16 [B][D]
    const unsigned short* __restrict__ w1t,   // bf16 [L][H][D]
    const float* __restrict__ b1,             // [L][H]
    const float* __restrict__ w2,             // [L][H]
    const float* __restrict__ b2,             // [L]
    float* __restrict__ out)                  // [B][L]
{
    // [dbuf][A=0/B=1][half][128 rows * 64 K] bf16 = 128 KiB
    __shared__ unsigned short ldsAB[2][2][2][128 * 64];
    __shared__ float partLds[256][4];         // separate: epilogue can't clobber staging

    const int bid = blockIdx.x;
    const int l   = (bid & 7) * 8 + ((bid >> 3) & 7);
    const int gi  = bid >> 6;                 // 0..3
    const int m00 = gi * 8 * BM;              // first tile's row base

    const int tid  = threadIdx.x;
    const int wid  = tid >> 6;
    const int lane = tid & 63;
    const int wr   = wid >> 2;   // 0..1
    const int wc   = wid & 3;    // 0..3
    const int g    = lane >> 4;  // 0..3
    const int rl   = lane & 15;

    const size_t ADV = (size_t)BM * D_SZ;     // A advance per output tile

    // Pre-swizzled global sources (rule #21): LDS dest linear, XOR swizzle
    // slot = kg ^ (row&7) baked into per-lane source address.
    const unsigned short* aSrc[2][2];
    const unsigned short* bSrc[2][2];
    #pragma unroll
    for (int h = 0; h < 2; ++h)
        #pragma unroll
        for (int c2 = 0; c2 < 2; ++c2) {
            const int q  = c2 * 512 + tid;
            const int r  = q >> 3;
            const int kg = (q & 7) ^ (r & 7);
            aSrc[h][c2] = xb  + (size_t)(m00 + h * 128 + r) * D_SZ + kg * 8;
            bSrc[h][c2] = w1t + ((size_t)l * H_SZ + h * 128 + r) * D_SZ + kg * 8;
        }

    // Epilogue constants — tile-invariant (label fixed per block), load ONCE
    // so no global loads (and no compiler vmcnt drain) inside the epilogue.
    float b1v[4], w2v[4];
    #pragma unroll
    for (int nf = 0; nf < 4; ++nf) {
        const int col = wc * 64 + nf * 16 + rl;
        b1v[nf] = b1[l * H_SZ + col];
        w2v[nf] = w2[l * H_SZ + col];
    }
    const float b2v = b2[l];

    f32x4 acc[8][4];
    bf16x8 af[2][2], bf[2][4];

    // One prologue per block: B(0), A(0), B(1)
    STAGE_B(0, 0); STAGE_B(0, 1);
    STAGE_A(0, 0); STAGE_A(0, 1);
    STAGE_B(1, 0); STAGE_B(1, 1);
    VMW(4);
    SBAR;

    #pragma unroll 1
    for (int o = 0; o < 8; ++o) {
        #pragma unroll
        for (int m = 0; m < 8; ++m)
            #pragma unroll
            for (int n = 0; n < 4; ++n) {
                acc[m][n][0] = 0.f; acc[m][n][1] = 0.f;
                acc[m][n][2] = 0.f; acc[m][n][3] = 0.f;
            }

        // iterations 0..6: pure current-tile stream (t3 = 2i+3 <= 15)
        #pragma unroll 1
        for (int i = 0; i < 7; ++i) {
            const int t1 = 2 * i + 1, t2 = 2 * i + 2, t3 = 2 * i + 3;
            DS_READ_B(0); DS_READ_A(0, 0); STAGE_A(t1, 0); SBAR; MFMA_QUAD(0); SBAR;
            DS_READ_A(0, 1); STAGE_A(t1, 1); SBAR; MFMA_QUAD(1); SBAR;
            DS_READ_A(0, 2); STAGE_B(t2, 0); SBAR; MFMA_QUAD(2); SBAR;
            DS_READ_A(0, 3); STAGE_B(t2, 1); SBAR; MFMA_QUAD(3); VMW(4); SBAR;
            DS_READ_B(1); DS_READ_A(1, 0); STAGE_A(t2, 0); SBAR; MFMA_QUAD(0); SBAR;
            DS_READ_A(1, 1); STAGE_A(t2, 1); SBAR; MFMA_QUAD(1); SBAR;
            DS_READ_A(1, 2); STAGE_B(t3, 0); SBAR; MFMA_QUAD(2); SBAR;
            DS_READ_A(1, 3); STAGE_B(t3, 1); SBAR; MFMA_QUAD(3); VMW(4); SBAR;
        }
        // iteration 7 (tiles 14,15): stage A(15), then NEXT tile's B(0), A'(0), B(1)
        // — recreates the prologue state, so the stream never drains.
        DS_READ_B(0); DS_READ_A(0, 0); STAGE_A(15, 0); SBAR; MFMA_QUAD(0); SBAR;
        DS_READ_A(0, 1); STAGE_A(15, 1); SBAR; MFMA_QUAD(1); SBAR;
        DS_READ_A(0, 2); STAGE_B(0, 0); SBAR; MFMA_QUAD(2); SBAR;
        DS_READ_A(0, 3); STAGE_B(0, 1); SBAR; MFMA_QUAD(3); VMW(4); SBAR;
        DS_READ_B(1); DS_READ_A(1, 0); STAGE_AN(0); SBAR; MFMA_QUAD(0); SBAR;
        DS_READ_A(1, 1); STAGE_AN(1); SBAR; MFMA_QUAD(1); SBAR;
        DS_READ_A(1, 2); STAGE_B(1, 0); SBAR; MFMA_QUAD(2); SBAR;
        DS_READ_A(1, 3); STAGE_B(1, 1); SBAR; MFMA_QUAD(3); VMW(4); SBAR;

        // ---- epilogue for tile o (overlaps in-flight staging of tile o+1) ----
        const int m0 = m00 + o * BM;
        #pragma unroll
        for (int mf = 0; mf < 8; ++mf) {
            #pragma unroll
            for (int r = 0; r < 4; ++r) {
                float p = 0.f;
                #pragma unroll
                for (int nf = 0; nf < 4; ++nf) {
                    float v = acc[mf][nf][r] + b1v[nf];
                    v = fmaxf(v, 0.f);
                    p += v * w2v[nf];
                }
                p += __shfl_xor(p, 1);
                p += __shfl_xor(p, 2);
                p += __shfl_xor(p, 4);
                p += __shfl_xor(p, 8);
                if (rl == 0)
                    partLds[wr * 128 + mf * 16 + g * 4 + r][wc] = p;
            }
        }
        __syncthreads();
        if (tid < BM) {
            float s = b2v;
            #pragma unroll
            for (int w = 0; w < 4; ++w) s += partLds[tid][w];
            out[(size_t)(m0 + tid) * L_SZ + l] = s;
        }
        __syncthreads();   // partLds safe to rewrite next tile

        // advance A sources to next output tile
        #pragma unroll
        for (int h = 0; h < 2; ++h)
            #pragma unroll
            for (int c2 = 0; c2 < 2; ++c2)
                aSrc[h][c2] += ADV;
    }
    VMW(0);   // drain leftover (harmless) stages before endpgm
}

extern "C" void kernel_launch(void* const* d_in, const int* in_sizes, int n_in,
                              void* d_out, int out_size, void* d_ws, size_t ws_size,
                              hipStream_t stream) {
    const float* x  = (const float*)d_in[0];
    const float* W1 = (const float*)d_in[1];
    const float* b1 = (const float*)d_in[2];
    const float* W2 = (const float*)d_in[3];
    const float* b2 = (const float*)d_in[4];
    float* out = (float*)d_out;

    unsigned short* xb  = (unsigned short*)d_ws;                 // 16 MB
    unsigned short* w1t = xb + (size_t)B_SZ * D_SZ;              // 32 MB

    cvt_x_kernel<<<(B_SZ * D_SZ / 4) / 256, 256, 0, stream>>>(x, xb);
    transpose_w1_kernel<<<L_SZ * 16 * 4, 256, 0, stream>>>(W1, w1t);
    ffn_gemm_kernel<<<256, 512, 0, stream>>>(xb, w1t, b1, W2, b2, out);
}